// Round 9
// baseline (371.635 us; speedup 1.0000x reference)
//
#include <hip/hip_runtime.h>

#define B_  16
#define T_  2048
#define L_  128
#define H_  512
#define F_  1024
#define EPS 1e-5f

#define GP   68                 // 64+4 LDS pad
#define GSM  (64 * GP * 2)      // 34816 B -> 4 blocks/CU LDS cap

// ---------------------------------------------------------------------------
// Job for the 64x64-tile GEMM (BK=64, TM=TN=4, 256 thr).
// amode: 0 dense row-major(lda=512) with A slab-sum (nsA/ssA);
//        1 Wc: rows<128 from A(lda), row128 from Aaux(be), out row128->C2;
//        2 tree: A-row -> pred[((r>>4)<<5)+16+(r&15)] (slab-sum nsA/ssA);
//          kc==0 block epilogue adds slab-sum of pred[((r>>4)<<5)+(r&15)];
//        3 x-gather: row r=(lag*16+b) -> x[b][T-1-lag][:], epilogue +Aaux[c]
// Output: C + kc*M*512 (one slab per kc). kLen multiple of 64.
// ---------------------------------------------------------------------------
struct Job {
    const float* A; const float* Aaux; const float* B; const float* Add;
    float* C; float* C2;
    int M, lda, kLen, nbx, nrt, amode, nsA, ssA;
};

__device__ __forceinline__ float4 jloadA(const Job& jb, int gr, int gk) {
    if (jb.amode == 1) {
        if (gr < 128)  return *(const float4*)(jb.A + (long)gr * jb.lda + gk);
        if (gr == 128) return *(const float4*)(jb.Aaux + gk);
        return make_float4(0.f, 0.f, 0.f, 0.f);
    }
    if (jb.amode == 3) {
        int b = gr & 15, lag = gr >> 4;
        return *(const float4*)(jb.A + ((long)b * T_ + (T_ - 1 - lag)) * L_ + gk);
    }
    int row = gr;
    if (jb.amode == 2) row = ((gr >> 4) << 5) + 16 + (gr & 15);
    else if (gr >= jb.M) return make_float4(0.f, 0.f, 0.f, 0.f);
    const float* p = jb.A + (long)row * 512 + gk;
    float4 s = *(const float4*)p;
    for (int q = 1; q < jb.nsA; ++q) {
        float4 t = *(const float4*)(p + (long)q * jb.ssA);
        s.x += t.x; s.y += t.y; s.z += t.z; s.w += t.w;
    }
    return s;
}

__device__ __forceinline__ void g64run(float* sm, const Job& jb, int rel) {
    float* As = sm;                 // [64][68] As[k][m]
    float* Bs = sm + 64 * GP;       // [64][68] Bs[k][n]
    const int tid = threadIdx.x, tx = tid & 15, ty = tid >> 4;
    const int bx = rel % jb.nbx;
    const int r  = rel / jb.nbx;
    const int by = r % jb.nrt;
    const int kc = r / jb.nrt;
    const int row0 = by * 64, col0 = bx * 64, kOff = kc * jb.kLen;

    float4 pa[4], pb[4];
#pragma unroll
    for (int t = 0; t < 4; ++t) {
        int f = tid + t * 256;
        pa[t] = jloadA(jb, row0 + (f >> 4), kOff + (f & 15) * 4);
        pb[t] = *(const float4*)(jb.B + (long)(kOff + (f >> 4)) * 512 + col0 + (f & 15) * 4);
    }
    float acc[4][4] = {};
    for (int k0 = 0; k0 < jb.kLen; k0 += 64) {
        __syncthreads();
#pragma unroll
        for (int t = 0; t < 4; ++t) {
            int f = tid + t * 256;
            int ar = f >> 4, ak = (f & 15) * 4;
            As[(ak + 0) * GP + ar] = pa[t].x;
            As[(ak + 1) * GP + ar] = pa[t].y;
            As[(ak + 2) * GP + ar] = pa[t].z;
            As[(ak + 3) * GP + ar] = pa[t].w;
            *(float4*)&Bs[(f >> 4) * GP + (f & 15) * 4] = pb[t];
        }
        __syncthreads();
        int kn = k0 + 64;
        if (kn < jb.kLen) {
#pragma unroll
            for (int t = 0; t < 4; ++t) {
                int f = tid + t * 256;
                pa[t] = jloadA(jb, row0 + (f >> 4), kOff + kn + (f & 15) * 4);
                pb[t] = *(const float4*)(jb.B + (long)(kOff + kn + (f >> 4)) * 512 +
                                         col0 + (f & 15) * 4);
            }
        }
#pragma unroll
        for (int kk = 0; kk < 64; ++kk) {
            float4 ra = *(float4*)&As[kk * GP + ty * 4];
            float4 rb = *(float4*)&Bs[kk * GP + tx * 4];
            acc[0][0] = fmaf(ra.x, rb.x, acc[0][0]);
            acc[0][1] = fmaf(ra.x, rb.y, acc[0][1]);
            acc[0][2] = fmaf(ra.x, rb.z, acc[0][2]);
            acc[0][3] = fmaf(ra.x, rb.w, acc[0][3]);
            acc[1][0] = fmaf(ra.y, rb.x, acc[1][0]);
            acc[1][1] = fmaf(ra.y, rb.y, acc[1][1]);
            acc[1][2] = fmaf(ra.y, rb.z, acc[1][2]);
            acc[1][3] = fmaf(ra.y, rb.w, acc[1][3]);
            acc[2][0] = fmaf(ra.z, rb.x, acc[2][0]);
            acc[2][1] = fmaf(ra.z, rb.y, acc[2][1]);
            acc[2][2] = fmaf(ra.z, rb.z, acc[2][2]);
            acc[2][3] = fmaf(ra.z, rb.w, acc[2][3]);
            acc[3][0] = fmaf(ra.w, rb.x, acc[3][0]);
            acc[3][1] = fmaf(ra.w, rb.y, acc[3][1]);
            acc[3][2] = fmaf(ra.w, rb.z, acc[3][2]);
            acc[3][3] = fmaf(ra.w, rb.w, acc[3][3]);
        }
    }
    long coff = (long)kc * jb.M * 512;
#pragma unroll
    for (int i = 0; i < 4; ++i) {
        int rr = row0 + ty * 4 + i;
        if (rr >= jb.M) continue;
        int c = col0 + tx * 4;
        float4 v = make_float4(acc[i][0], acc[i][1], acc[i][2], acc[i][3]);
        if (jb.amode == 2 && kc == 0) {
            long prow = (long)(((rr >> 4) << 5) + (rr & 15)) * 512;
            const float* ap = jb.Add + prow + c;
            for (int q = 0; q < jb.nsA; ++q) {
                float4 ad = *(const float4*)(ap + (long)q * jb.ssA);
                v.x += ad.x; v.y += ad.y; v.z += ad.z; v.w += ad.w;
            }
        }
        if (jb.amode == 3) {
            v.x += jb.Aaux[c]; v.y += jb.Aaux[c + 1];
            v.z += jb.Aaux[c + 2]; v.w += jb.Aaux[c + 3];
        }
        if (jb.amode == 1 && rr == 128)
            *(float4*)(jb.C2 + c) = v;
        else
            *(float4*)(jb.C + coff + (long)rr * 512 + c) = v;
    }
}

struct Pack { Job j[2]; int n0; };

__global__ __launch_bounds__(256) void gstage(Pack p) {
    __shared__ float sm[GSM];
    int b = blockIdx.x;
    if (b < p.n0) g64run(sm, p.j[0], b);
    else          g64run(sm, p.j[1], b - p.n0);
}

// ---------------------------------------------------------------------------
// Tail split-K GEMM: BM=16, BN=64, BK=64, 4 out/thread, slab outputs.
// MODE 0 (z): A=[sum8 Y5s nodes1..3 | x_last] K=1664, B=[P32;P64;P96;Wr]
// MODE 1: A=zn, B=W1 (ldb=1024)
// MODE 2: A=relu(b1+sum8 h1p), B=W2
// ---------------------------------------------------------------------------
struct TP {
    const float* Y5s; const float* P32; const float* P64; const float* P96;
    const float* x; const float* Wr; const float* zn; const float* W1;
    const float* h1p; const float* b1; const float* W2;
    float* outp; int nbx, kLen;
};

template <int MODE>
__device__ __forceinline__ float4 ta4(const TP& tp, int b, int gk) {
    if (MODE == 0) {
        if (gk < 1536) {
            int seg = gk >> 9, inner = gk & 511;
            const float* p = tp.Y5s + (long)((seg + 1) * 16 + b) * 512 + inner;
            float4 s = *(const float4*)p;
#pragma unroll
            for (int q = 1; q < 8; ++q) {
                float4 t = *(const float4*)(p + (long)q * 64 * 512);
                s.x += t.x; s.y += t.y; s.z += t.z; s.w += t.w;
            }
            return s;
        }
        return *(const float4*)(tp.x + ((long)b * T_ + T_ - 1) * L_ + gk - 1536);
    } else if (MODE == 1) {
        return *(const float4*)(tp.zn + (long)b * H_ + gk);
    } else {
        float4 s = *(const float4*)(tp.b1 + gk);
#pragma unroll
        for (int q = 0; q < 8; ++q) {
            float4 h = *(const float4*)(tp.h1p + (long)q * 16 * F_ + (long)b * F_ + gk);
            s.x += h.x; s.y += h.y; s.z += h.z; s.w += h.w;
        }
        return make_float4(fmaxf(s.x, 0.f), fmaxf(s.y, 0.f),
                           fmaxf(s.z, 0.f), fmaxf(s.w, 0.f));
    }
}

template <int MODE>
__device__ __forceinline__ float4 tb4(const TP& tp, int kr, int c) {
    if (MODE == 0) {
        if (kr < 512)  return *(const float4*)(tp.P32 + (long)kr * 512 + c);
        if (kr < 1024) return *(const float4*)(tp.P64 + (long)(kr - 512) * 512 + c);
        if (kr < 1536) return *(const float4*)(tp.P96 + (long)(kr - 1024) * 512 + c);
        return *(const float4*)(tp.Wr + (long)(kr - 1536) * 512 + c);
    } else if (MODE == 1) {
        return *(const float4*)(tp.W1 + (long)kr * F_ + c);
    } else {
        return *(const float4*)(tp.W2 + (long)kr * H_ + c);
    }
}

template <int MODE>
__global__ __launch_bounds__(256) void tstage(TP tp) {
    constexpr int LDC = (MODE == 1) ? F_ : H_;
    __shared__ float sm[64 * 20 + 64 * 68];
    float* As = sm;
    float* Bs = sm + 64 * 20;
    const int tid = threadIdx.x, tx = tid & 15, ty = tid >> 4;
    const int kc = blockIdx.x / tp.nbx;
    const int col0 = (blockIdx.x % tp.nbx) * 64;
    const int kOff = kc * tp.kLen;

    float4 pa, pb[4];
    pa = ta4<MODE>(tp, ty, kOff + tx * 4);
#pragma unroll
    for (int t = 0; t < 4; ++t) {
        int f = tid + t * 256;
        pb[t] = tb4<MODE>(tp, kOff + (f >> 4), col0 + (f & 15) * 4);
    }
    float acc[4] = {};
    for (int k0 = 0; k0 < tp.kLen; k0 += 64) {
        __syncthreads();
        {
            int kk = tx * 4;
            As[(kk + 0) * 20 + ty] = pa.x;
            As[(kk + 1) * 20 + ty] = pa.y;
            As[(kk + 2) * 20 + ty] = pa.z;
            As[(kk + 3) * 20 + ty] = pa.w;
        }
#pragma unroll
        for (int t = 0; t < 4; ++t) {
            int f = tid + t * 256;
            *(float4*)&Bs[(f >> 4) * 68 + (f & 15) * 4] = pb[t];
        }
        __syncthreads();
        int kn = k0 + 64;
        if (kn < tp.kLen) {
            pa = ta4<MODE>(tp, ty, kOff + kn + tx * 4);
#pragma unroll
            for (int t = 0; t < 4; ++t) {
                int f = tid + t * 256;
                pb[t] = tb4<MODE>(tp, kOff + kn + (f >> 4), col0 + (f & 15) * 4);
            }
        }
#pragma unroll
        for (int kk = 0; kk < 64; ++kk) {
            float ra = As[kk * 20 + ty];
            float4 rb = *(float4*)&Bs[kk * 68 + tx * 4];
            acc[0] = fmaf(ra, rb.x, acc[0]);
            acc[1] = fmaf(ra, rb.y, acc[1]);
            acc[2] = fmaf(ra, rb.z, acc[2]);
            acc[3] = fmaf(ra, rb.w, acc[3]);
        }
    }
    float* dst = tp.outp + (long)kc * 16 * LDC + (long)ty * LDC + col0 + tx * 4;
    *(float4*)dst = make_float4(acc[0], acc[1], acc[2], acc[3]);
}

// z = br + sum26 zp + sum8 Y5s(node0); LayerNorm -> zn.  grid=16
__global__ __launch_bounds__(256) void zln(
    const float* __restrict__ zp, const float* __restrict__ Y5s,
    const float* __restrict__ br, const float* __restrict__ lng,
    const float* __restrict__ lnb, float* __restrict__ zn)
{
    __shared__ float red1[4], red2[4];
    const int b = blockIdx.x, tid = threadIdx.x;
    float z[2];
#pragma unroll
    for (int jj = 0; jj < 2; ++jj) {
        int c = tid + jj * 256;
        float s = br[c];
#pragma unroll
        for (int q = 0; q < 26; ++q) s += zp[(long)q * 16 * H_ + (long)b * H_ + c];
#pragma unroll
        for (int q = 0; q < 8; ++q) s += Y5s[(long)q * 64 * 512 + (long)b * 512 + c];
        z[jj] = s;
    }
    float s1 = z[0] + z[1];
    float s2 = z[0] * z[0] + z[1] * z[1];
#pragma unroll
    for (int off = 32; off > 0; off >>= 1) {
        s1 += __shfl_down(s1, off, 64);
        s2 += __shfl_down(s2, off, 64);
    }
    int wid = tid >> 6, lane = tid & 63;
    if (lane == 0) { red1[wid] = s1; red2[wid] = s2; }
    __syncthreads();
    float S1 = red1[0] + red1[1] + red1[2] + red1[3];
    float S2 = red2[0] + red2[1] + red2[2] + red2[3];
    float mu  = S1 * (1.0f / H_);
    float var = S2 * (1.0f / H_) - mu * mu;
    float rs  = rsqrtf(var + EPS);
#pragma unroll
    for (int jj = 0; jj < 2; ++jj) {
        int c = tid + jj * 256;
        zn[(long)b * H_ + c] = (z[jj] - mu) * rs * lng[c] + lnb[c];
    }
}

// out = b2 + sum16 op.  grid=32
__global__ __launch_bounds__(256) void ored(
    const float* __restrict__ op, const float* __restrict__ b2,
    float* __restrict__ out)
{
    int b = blockIdx.x >> 1;
    int c = (blockIdx.x & 1) * 256 + threadIdx.x;
    float s = b2[c];
#pragma unroll
    for (int q = 0; q < 16; ++q) s += op[(long)q * 16 * H_ + (long)b * H_ + c];
    out[(long)b * H_ + c] = s;
}

// ---------------------------------------------------------------------------
extern "C" void kernel_launch(void* const* d_in, const int* in_sizes, int n_in,
                              void* d_out, int out_size, void* d_ws, size_t ws_size,
                              hipStream_t stream) {
    const float* x    = (const float*)d_in[0];
    const float* We   = (const float*)d_in[1];
    const float* be   = (const float*)d_in[2];
    const float* Wb   = (const float*)d_in[3];
    const float* Amat = (const float*)d_in[4];
    const float* Wr   = (const float*)d_in[5];
    const float* br   = (const float*)d_in[6];
    const float* lng  = (const float*)d_in[7];
    const float* lnb  = (const float*)d_in[8];
    const float* W1   = (const float*)d_in[9];
    const float* b1   = (const float*)d_in[10];
    const float* W2   = (const float*)d_in[11];
    const float* b2   = (const float*)d_in[12];
    float* out = (float*)d_out;

    float* ws  = (float*)d_ws;
    float* Wc  = ws;                         // 128x512
    float* bc  = Wc + 128 * 512;             // 512
    float* U0  = bc + 512;                   // 2048x512
    float* Y1s = U0 + 2048 * 512;            // 2 x 1024x512
    float* Y2s = Y1s + 2 * 1024 * 512;       // 2 x 512x512
    float* Y3s = Y2s + 2 * 512 * 512;        // 4 x 256x512
    float* Y4s = Y3s + 4 * 256 * 512;        // 4 x 128x512
    float* Y5s = Y4s + 4 * 128 * 512;        // 8 x 64x512
    float* P2  = Y5s + 8 * 64 * 512;         // dense powers, 512^2 each
    float* P4  = P2 + 512 * 512;
    float* P8  = P4 + 512 * 512;
    float* P16 = P8 + 512 * 512;
    float* P32 = P16 + 512 * 512;
    float* P64 = P32 + 512 * 512;
    float* P96 = P64 + 512 * 512;
    float* zp  = P96 + 512 * 512;            // 26 x 16 x 512
    float* zn  = zp + 26 * B_ * H_;          // 16 x 512
    float* h1p = zn + B_ * H_;               // 8 x 16 x 1024
    float* op  = h1p + 8 * B_ * F_;          // 16 x 16 x 512

    // S0: Wc=[We;be]@Wb (24)  ||  P2 = A@A dense (64)
    {
        Pack p;
        p.j[0] = {We, be, Wb, nullptr, Wc, bc, 129, 256, 256, 8, 3, 1, 1, 0};
        p.j[1] = {Amat, nullptr, Amat, nullptr, P2, nullptr, 512, 512, 512, 8, 8, 0, 1, 0};
        p.n0 = 24;
        gstage<<<88, 256, 0, stream>>>(p);
    }
    // S1: U0 = x-gather@Wc + bc (256)  ||  P4 = P2@P2 dense (64)
    {
        Pack p;
        p.j[0] = {x, bc, Wc, nullptr, U0, nullptr, 2048, 0, 128, 8, 32, 3, 1, 0};
        p.j[1] = {P2, nullptr, P2, nullptr, P4, nullptr, 512, 512, 512, 8, 8, 0, 1, 0};
        p.n0 = 256;
        gstage<<<320, 256, 0, stream>>>(p);
    }
    // S2: Y1s = tree(U0)@A split2 (256)  ||  P8 = P4@P4 (64)
    {
        Pack p;
        p.j[0] = {U0, nullptr, Amat, U0, Y1s, nullptr, 1024, 512, 256, 8, 16, 2, 1, 0};
        p.j[1] = {P4, nullptr, P4, nullptr, P8, nullptr, 512, 512, 512, 8, 8, 0, 1, 0};
        p.n0 = 256;
        gstage<<<320, 256, 0, stream>>>(p);
    }
    // S3: Y2s = tree(sum2 Y1s)@P2 split2 (128)  ||  P16 = P8@P8 (64)
    {
        Pack p;
        p.j[0] = {Y1s, nullptr, P2, Y1s, Y2s, nullptr, 512, 512, 256, 8, 8, 2, 2, 1024 * 512};
        p.j[1] = {P8, nullptr, P8, nullptr, P16, nullptr, 512, 512, 512, 8, 8, 0, 1, 0};
        p.n0 = 128;
        gstage<<<192, 256, 0, stream>>>(p);
    }
    // S4: Y3s = tree(sum2 Y2s)@P4 split4 (128)  ||  P32 = P16@P16 (64)
    {
        Pack p;
        p.j[0] = {Y2s, nullptr, P4, Y2s, Y3s, nullptr, 256, 512, 128, 8, 4, 2, 2, 512 * 512};
        p.j[1] = {P16, nullptr, P16, nullptr, P32, nullptr, 512, 512, 512, 8, 8, 0, 1, 0};
        p.n0 = 128;
        gstage<<<192, 256, 0, stream>>>(p);
    }
    // S5: Y4s = tree(sum4 Y3s)@P8 split4 (64)  ||  P64 = P32@P32 (64)
    {
        Pack p;
        p.j[0] = {Y3s, nullptr, P8, Y3s, Y4s, nullptr, 128, 512, 128, 8, 2, 2, 4, 256 * 512};
        p.j[1] = {P32, nullptr, P32, nullptr, P64, nullptr, 512, 512, 512, 8, 8, 0, 1, 0};
        p.n0 = 64;
        gstage<<<128, 256, 0, stream>>>(p);
    }
    // S6: Y5s = tree(sum4 Y4s)@P16 split8 (64)  ||  P96 = P32@P64 (64)
    {
        Pack p;
        p.j[0] = {Y4s, nullptr, P16, Y4s, Y5s, nullptr, 64, 512, 64, 8, 1, 2, 4, 128 * 512};
        p.j[1] = {P32, nullptr, P64, nullptr, P96, nullptr, 512, 512, 512, 8, 8, 0, 1, 0};
        p.n0 = 64;
        gstage<<<128, 256, 0, stream>>>(p);
    }
    TP tp;
    tp.Y5s = Y5s; tp.P32 = P32; tp.P64 = P64; tp.P96 = P96;
    tp.x = x; tp.Wr = Wr; tp.zn = zn; tp.W1 = W1; tp.h1p = h1p;
    tp.b1 = b1; tp.W2 = W2;

    // S7: zp (K=1664, 26 kc x 8 col-tiles = 208)
    { TP t = tp; t.outp = zp; t.nbx = 8; t.kLen = 64;
      tstage<0><<<208, 256, 0, stream>>>(t); }
    // S8: zln
    zln<<<16, 256, 0, stream>>>(zp, Y5s, br, lng, lnb, zn);
    // S9: h1p = zn@W1 (K=512, 8 kc x 16 = 128)
    { TP t = tp; t.outp = h1p; t.nbx = 16; t.kLen = 64;
      tstage<1><<<128, 256, 0, stream>>>(t); }
    // S10: op = relu(b1+sum8 h1p)@W2 (K=1024, 16 kc x 8 = 128)
    { TP t = tp; t.outp = op; t.nbx = 8; t.kLen = 64;
      tstage<2><<<128, 256, 0, stream>>>(t); }
    // S11: out = b2 + sum16 op
    ored<<<32, 256, 0, stream>>>(op, b2, out);
}